// Round 15
// baseline (124.176 us; speedup 1.0000x reference)
//
#include <hip/hip_runtime.h>

#define BS 32
#define NE 512
#define DMODEL 512
#define HEADS 8
#define EMB 64
#define FFH 256
#define MTOK (BS*NE)   // 16384

typedef unsigned short u16;
typedef short v8s __attribute__((ext_vector_type(8)));
typedef float f32x4 __attribute__((ext_vector_type(4)));
typedef u16 u16x4 __attribute__((ext_vector_type(4)));

#define GLOAD16(G, L) \
  __builtin_amdgcn_global_load_lds((const __attribute__((address_space(1))) unsigned int*)(G), \
      (__attribute__((address_space(3))) unsigned int*)(L), 16, 0, 0)

static __device__ __forceinline__ unsigned cvt_pk_bf16(float lo, float hi) {
    unsigned r;
    asm("v_cvt_pk_bf16_f32 %0, %1, %2" : "=v"(r) : "v"(lo), "v"(hi));
    return r;
}

static __device__ __forceinline__ u16 f2bf_bits(float f) {
    unsigned u = __float_as_uint(f);
    u += 0x7fffu + ((u >> 16) & 1u);   // round-to-nearest-even
    return (u16)(u >> 16);
}
static __device__ __forceinline__ float bflo(unsigned w) { return __uint_as_float(w << 16); }
static __device__ __forceinline__ float bfhi(unsigned w) { return __uint_as_float(w & 0xffff0000u); }

// ---------------- fused conversion ----------------
__global__ __launch_bounds__(256) void cvt_all_kernel(
    const float* __restrict__ x, u16* __restrict__ xb,
    const float* __restrict__ Wq, const float* __restrict__ Wk, const float* __restrict__ Wv,
    const float* __restrict__ W1, const float* __restrict__ W2,
    u16* __restrict__ WqkvT, u16* __restrict__ W1T, u16* __restrict__ W2T)
{
    int idx = blockIdx.x * 256 + threadIdx.x;
    if (idx < 2097152) {
        float4 v = ((const float4*)x)[idx];
        u16x4 o = { f2bf_bits(v.x), f2bf_bits(v.y), f2bf_bits(v.z), f2bf_bits(v.w) };
        ((u16x4*)xb)[idx] = o;
        return;
    }
    int widx = idx - 2097152;                 // 0 .. 1048575
    if (widx < 786432) {
        int w = widx >> 18, rem = widx & 262143;
        int k = rem >> 9, n = rem & 511;
        const float* src = (w == 0) ? Wq : (w == 1) ? Wk : Wv;
        WqkvT[(size_t)(w*512 + n)*512 + k] = f2bf_bits(src[rem]);
    } else if (widx < 917504) {
        int rem = widx - 786432;              // W1: [512][256]
        int k = rem >> 8, n = rem & 255;
        W1T[n*512 + k] = f2bf_bits(W1[rem]);
    } else if (widx < 1048576) {
        int rem = widx - 917504;              // W2: [256][512]
        int k = rem >> 9, n = rem & 511;
        W2T[n*256 + k] = f2bf_bits(W2[rem]);
    }
}

// ---------------- fused QKV GEMM: 256x128 tile, 3-buffer depth-2 pipeline ----------------
// 512 threads / 8 waves (wave tile 64x64), BK=64, LDS 3 x (32KB A + 16KB B) = 144KB.
// Counted vmcnt(6): stage(t+1) stays in flight across the barrier; stage(t+2) issued
// right after (its buffer freed by compute(t-1), certified by this barrier).
// Cover window for each stage = 2 full compute phases.
// 12 col-panels: 0-3 Q (swapped acc, pre-scaled), 4-7 K (swapped), 8-11 V (normal -> vT).
__global__ __launch_bounds__(512) void qkv_kernel(
    const u16* __restrict__ A, const u16* __restrict__ BT,
    const float* __restrict__ bsQ, const float* __restrict__ bsK, const float* __restrict__ bsV,
    u16* __restrict__ oQ, u16* __restrict__ oK, u16* __restrict__ oVT)
{
    extern __shared__ char smem[];   // [0,96K): A bufs x3 (32KB); [96K,144K): B bufs x3 (16KB)
    const int tid = threadIdx.x;
    const int wave = tid >> 6, lane = tid & 63;
    const int lr = lane & 15, lg = lane >> 4, lr7 = lr & 7;
    const int id = blockIdx.x;
    const int rr = id & 7, qq = id >> 3;          // 768 blocks: 64 row x 12 col
    const int gk = qq / 12, colBlk = qq - gk*12;
    const int rowBlk = gk*8 + rr;
    const int aRow0 = rowBlk*256, bRow0 = colBlk*128;
    const int wlo = (wave >> 1)*64, wco = (wave & 1)*64;
    const int srow = tid >> 3, schunk = tid & 7;  // srow 0..63
    const int soff = ((schunk ^ (srow & 7)) << 3);
    const bool isV = (bRow0 >= 1024);

    // stage one 256x64 A-tile (4 loads/thread) + 128x64 B-tile (2 loads/thread)
    auto stage = [&](int bsel, int k0) {
        #pragma unroll
        for (int i = 0; i < 4; ++i)
            GLOAD16(A + (size_t)(aRow0 + i*64 + srow)*512 + k0 + soff,
                    smem + bsel*32768 + i*8192 + wave*1024);
        #pragma unroll
        for (int i = 0; i < 2; ++i)
            GLOAD16(BT + (size_t)(bRow0 + i*64 + srow)*512 + k0 + soff,
                    smem + 98304 + bsel*16384 + i*8192 + wave*1024);
    };

    stage(0, 0);
    stage(1, 64);

    f32x4 acc[4][4] = {};
    #pragma unroll
    for (int t = 0; t < 8; ++t) {
        const int bsel = t % 3;
        if (t < 7) { asm volatile("s_waitcnt vmcnt(6)" ::: "memory"); }
        else       { asm volatile("s_waitcnt vmcnt(0)" ::: "memory"); }
        __builtin_amdgcn_s_barrier();
        if (t + 2 < 8) stage((t + 2) % 3, (t + 2) * 64);
        const char* Abase = smem + bsel*32768;
        const char* Bbase = smem + 98304 + bsel*16384;
        #pragma unroll
        for (int kk = 0; kk < 2; ++kk) {
            v8s af[4], bf[4];
            #pragma unroll
            for (int i = 0; i < 4; ++i) {
                af[i] = *(const v8s*)(Abase + (wlo + i*16 + lr)*128 + ((((kk<<2)|lg) ^ lr7) << 4));
                bf[i] = *(const v8s*)(Bbase + (wco + i*16 + lr)*128 + ((((kk<<2)|lg) ^ lr7) << 4));
            }
            if (isV) {
                #pragma unroll
                for (int i = 0; i < 4; ++i)
                    #pragma unroll
                    for (int j = 0; j < 4; ++j)
                        acc[i][j] = __builtin_amdgcn_mfma_f32_16x16x32_bf16(af[i], bf[j], acc[i][j], 0, 0, 0);
            } else {
                #pragma unroll
                for (int i = 0; i < 4; ++i)
                    #pragma unroll
                    for (int j = 0; j < 4; ++j)
                        acc[i][j] = __builtin_amdgcn_mfma_f32_16x16x32_bf16(bf[j], af[i], acc[i][j], 0, 0, 0);
            }
        }
    }

    if (isV) {
        // normal acc: col = lr (d-col), rows = 4lg+{0..3} (tokens) -> pack into vT row
        #pragma unroll
        for (int j = 0; j < 4; ++j) {
            int col = (bRow0 & 511) + wco + j*16 + lr;
            float bv = bsV[col];
            int hh = col >> 6, d = col & 63;
            #pragma unroll
            for (int i = 0; i < 4; ++i) {
                int t0 = aRow0 + wlo + i*16 + lg*4;
                int bb = t0 >> 9, tr = t0 & 511;
                unsigned lo = cvt_pk_bf16(acc[i][j][0] + bv, acc[i][j][1] + bv);
                unsigned hi = cvt_pk_bf16(acc[i][j][2] + bv, acc[i][j][3] + bv);
                *(uint2*)(oVT + ((size_t)((bb*HEADS + hh)*EMB + d))*NE + tr) = make_uint2(lo, hi);
            }
        }
    } else {
        const int sel = (bRow0 >> 9) & 1;          // 0 = Q, 1 = K
        u16* dst = sel ? oK : oQ;
        const float* bias = sel ? bsK : bsQ;
        const int cb = bRow0 & 511;
        #pragma unroll
        for (int j = 0; j < 4; ++j) {
            int col0 = cb + wco + j*16 + lg*4;
            float4 b4 = *(const float4*)&bias[col0];
            #pragma unroll
            for (int i = 0; i < 4; ++i) {
                int row = aRow0 + wlo + i*16 + lr;
                float v0 = acc[i][j][0] + b4.x, v1 = acc[i][j][1] + b4.y;
                float v2 = acc[i][j][2] + b4.z, v3 = acc[i][j][3] + b4.w;
                if (sel == 0) {
                    const float SCL = 0.18033688011112042f;   // 0.125*log2(e)
                    v0 *= SCL; v1 *= SCL; v2 *= SCL; v3 *= SCL;
                }
                *(uint2*)(dst + (size_t)row*DMODEL + col0)
                    = make_uint2(cvt_pk_bf16(v0, v1), cvt_pk_bf16(v2, v3));
            }
        }
    }
}

// ---------------- attention (setprio around MFMA clusters) ----------------
__global__ __launch_bounds__(512, 2) void attn_kernel(
    const u16* __restrict__ Q, const u16* __restrict__ Kb,
    const u16* __restrict__ VT, u16* __restrict__ O)
{
    extern __shared__ char smem[];
    const int b = blockIdx.x >> 3, h = blockIdx.x & 7;
    const int tid = threadIdx.x, wave = tid >> 6, lane = tid & 63;
    const int lr = lane & 15, lg = lane >> 4, lr7 = lr & 7;

    const int srow = tid >> 3, schunk = tid & 7;
    const int soff = ((schunk ^ (srow & 7)) << 3);
    #pragma unroll
    for (int i = 0; i < 8; ++i)
        GLOAD16(Kb + (size_t)(b*NE + i*64 + srow)*DMODEL + h*EMB + soff,
                (char*)smem + i*8192 + wave*1024);
    #pragma unroll
    for (int i = 0; i < 8; ++i) {
        int row = i*8 + wave;
        GLOAD16(VT + (size_t)((b*HEADS + h)*EMB + row)*NE + lane*8,
                (char*)smem + 65536 + row*1040);
    }

    const int q0 = wave*64;
    v8s qa[4][2];
    #pragma unroll
    for (int ti = 0; ti < 4; ++ti) {
        const u16* qr = Q + (size_t)(b*NE + q0 + ti*16 + lr)*DMODEL + h*EMB;
        qa[ti][0] = *(const v8s*)(qr + lg*8);
        qa[ti][1] = *(const v8s*)(qr + 32 + lg*8);
    }
    __syncthreads();

    f32x4 o[4][4] = {};
    float ssum[4] = {0.f, 0.f, 0.f, 0.f};

    #pragma unroll 1
    for (int c = 0; c < 16; ++c) {
        const char* kr0 = (const char*)smem + ((2*c  )*16 + lr)*128;
        const char* kr1 = (const char*)smem + ((2*c+1)*16 + lr)*128;
        v8s kA0 = *(const v8s*)(kr0 + ((lg ^ lr7) << 4));
        v8s kA1 = *(const v8s*)(kr0 + (((4|lg) ^ lr7) << 4));
        v8s kB0 = *(const v8s*)(kr1 + ((lg ^ lr7) << 4));
        v8s kB1 = *(const v8s*)(kr1 + (((4|lg) ^ lr7) << 4));
        v8s vf[4];
        #pragma unroll
        for (int dt = 0; dt < 4; ++dt) {
            const char* vr = (const char*)smem + 65536 + (dt*16 + lr)*1040 + c*64 + lg*8;
            uint2 lo = *(const uint2*)(vr);
            uint2 hi = *(const uint2*)(vr + 32);
            uint4 u = make_uint4(lo.x, lo.y, hi.x, hi.y);
            vf[dt] = *(v8s*)&u;
        }
        #pragma unroll
        for (int ti = 0; ti < 4; ++ti) {
            __builtin_amdgcn_s_setprio(1);
            f32x4 s0 = {0.f,0.f,0.f,0.f}, s1 = {0.f,0.f,0.f,0.f};
            s0 = __builtin_amdgcn_mfma_f32_16x16x32_bf16(kA0, qa[ti][0], s0, 0, 0, 0);
            s0 = __builtin_amdgcn_mfma_f32_16x16x32_bf16(kA1, qa[ti][1], s0, 0, 0, 0);
            s1 = __builtin_amdgcn_mfma_f32_16x16x32_bf16(kB0, qa[ti][0], s1, 0, 0, 0);
            s1 = __builtin_amdgcn_mfma_f32_16x16x32_bf16(kB1, qa[ti][1], s1, 0, 0, 0);
            __builtin_amdgcn_s_setprio(0);
            float p0 = exp2f(s0[0]), p1 = exp2f(s0[1]), p2 = exp2f(s0[2]), p3 = exp2f(s0[3]);
            float r0 = exp2f(s1[0]), r1 = exp2f(s1[1]), r2 = exp2f(s1[2]), r3 = exp2f(s1[3]);
            ssum[ti] += ((p0 + p1) + (p2 + p3)) + ((r0 + r1) + (r2 + r3));
            unsigned a0 = cvt_pk_bf16(p0, p1), a1 = cvt_pk_bf16(p2, p3);
            unsigned b0 = cvt_pk_bf16(r0, r1), b1 = cvt_pk_bf16(r2, r3);
            uint4 pu = make_uint4(a0, a1, b0, b1);
            v8s pb = *(v8s*)&pu;
            __builtin_amdgcn_s_setprio(1);
            #pragma unroll
            for (int dt = 0; dt < 4; ++dt)
                o[ti][dt] = __builtin_amdgcn_mfma_f32_16x16x32_bf16(vf[dt], pb, o[ti][dt], 0, 0, 0);
            __builtin_amdgcn_s_setprio(0);
        }
    }

    __syncthreads();

    float rinv[4];
    #pragma unroll
    for (int ti = 0; ti < 4; ++ti) {
        float v = ssum[ti];
        v += __shfl_xor(v, 16);
        v += __shfl_xor(v, 32);
        rinv[ti] = 1.f / v;
    }

    char* ow = (char*)smem + wave*10240;
    #pragma unroll
    for (int ti = 0; ti < 4; ++ti) {
        #pragma unroll
        for (int dt = 0; dt < 4; ++dt) {
            unsigned d0 = cvt_pk_bf16(o[ti][dt][0]*rinv[ti], o[ti][dt][1]*rinv[ti]);
            unsigned d1 = cvt_pk_bf16(o[ti][dt][2]*rinv[ti], o[ti][dt][3]*rinv[ti]);
            *(uint2*)(ow + (ti*16 + lr)*160 + dt*32 + lg*8) = make_uint2(d0, d1);
        }
    }
    __asm__ volatile("s_waitcnt lgkmcnt(0)" ::: "memory");
    #pragma unroll
    for (int it = 0; it < 8; ++it) {
        int rr2 = it*8 + (lane >> 3);
        uint4 v = *(const uint4*)(ow + rr2*160 + (lane & 7)*16);
        *(uint4*)(O + (size_t)(b*NE + q0 + rr2)*DMODEL + h*EMB + (lane & 7)*8) = v;
    }
}

// ---------------- grand fused LN1 + FF1 + relu + FF2 + residual + LN2 ----------------
__global__ __launch_bounds__(512) void ffln_kernel(
    const u16* __restrict__ At, const u16* __restrict__ xb,
    const float* __restrict__ g1, const float* __restrict__ be1,
    const u16* __restrict__ W1T, const float* __restrict__ b1,
    const u16* __restrict__ W2T, const float* __restrict__ b2,
    const float* __restrict__ g2, const float* __restrict__ be2,
    float* __restrict__ out)
{
    extern __shared__ char smem[];
    char* H   = smem;              // [64 rows][1024B], chunk16 ^ (row&7)
    char* F1  = smem + 65536;      // [64 rows][512B]
    char* BST = smem + 98304;      // 32KB weight staging
    float* Ps = (float*)(smem + 131072);   // [64][2] sum partials
    float* Pq = Ps + 128;                  // [64][2] sq partials

    const int tid = threadIdx.x, wave = tid >> 6, lane = tid & 63;
    const int lr = lane & 15, lg = lane >> 4, lr7 = lr & 7;
    const int r0 = blockIdx.x * 64;

    #pragma unroll
    for (int it = 0; it < 8; ++it) {
        int r = wave*8 + it;
        uint4 av = *(const uint4*)(At + (size_t)(r0 + r)*512 + lane*8);
        uint4 xv = *(const uint4*)(xb + (size_t)(r0 + r)*512 + lane*8);
        float v0 = bflo(av.x) + bflo(xv.x), v1 = bfhi(av.x) + bfhi(xv.x);
        float v2 = bflo(av.y) + bflo(xv.y), v3 = bfhi(av.y) + bfhi(xv.y);
        float v4 = bflo(av.z) + bflo(xv.z), v5 = bfhi(av.z) + bfhi(xv.z);
        float v6 = bflo(av.w) + bflo(xv.w), v7 = bfhi(av.w) + bfhi(xv.w);
        float s = ((v0+v1)+(v2+v3)) + ((v4+v5)+(v6+v7));
        float q = ((v0*v0+v1*v1)+(v2*v2+v3*v3)) + ((v4*v4+v5*v5)+(v6*v6+v7*v7));
        #pragma unroll
        for (int d = 1; d < 64; d <<= 1) { s += __shfl_xor(s, d); q += __shfl_xor(q, d); }
        float mu = s * (1.f/512.f);
        float rs = rsqrtf(q * (1.f/512.f) - mu*mu + 1e-5f);
        float4 gA = *(const float4*)(g1 + lane*8), gB = *(const float4*)(g1 + lane*8 + 4);
        float4 eA = *(const float4*)(be1 + lane*8), eB = *(const float4*)(be1 + lane*8 + 4);
        float h0 = (v0-mu)*rs*gA.x + eA.x, h1 = (v1-mu)*rs*gA.y + eA.y;
        float h2 = (v2-mu)*rs*gA.z + eA.z, h3 = (v3-mu)*rs*gA.w + eA.w;
        float h4 = (v4-mu)*rs*gB.x + eB.x, h5 = (v5-mu)*rs*gB.y + eB.y;
        float h6 = (v6-mu)*rs*gB.z + eB.z, h7 = (v7-mu)*rs*gB.w + eB.w;
        uint4 hw = make_uint4(cvt_pk_bf16(h0,h1), cvt_pk_bf16(h2,h3),
                              cvt_pk_bf16(h4,h5), cvt_pk_bf16(h6,h7));
        *(uint4*)(H + r*1024 + ((lane ^ (r & 7)) << 4)) = hw;
    }
    __syncthreads();

    const int wr = (wave & 3)*16, wcB = (wave >> 2)*128;
    f32x4 acc1[8] = {};
    for (int s8 = 0; s8 < 8; ++s8) {
        int k0 = s8*64;
        #pragma unroll
        for (int i = 0; i < 4; ++i) {
            int slot = i*512 + tid;
            int row = slot >> 3, ch = slot & 7;
            GLOAD16(W1T + (size_t)row*512 + k0 + ((ch ^ (row & 7)) << 3),
                    BST + i*8192 + wave*1024);
        }
        __syncthreads();
        #pragma unroll
        for (int kk = 0; kk < 2; ++kk) {
            v8s af = *(const v8s*)(H + (wr + lr)*1024 + ((s8*8 + ((kk*4 + lg) ^ lr7)) << 4));
            v8s bf[8];
            #pragma unroll
            for (int j = 0; j < 8; ++j)
                bf[j] = *(const v8s*)(BST + (wcB + j*16 + lr)*128 + ((((kk<<2)|lg) ^ lr7) << 4));
            #pragma unroll
            for (int j = 0; j < 8; ++j)
                acc1[j] = __builtin_amdgcn_mfma_f32_16x16x32_bf16(bf[j], af, acc1[j], 0, 0, 0);
        }
        __syncthreads();
    }

    {
        int row = wr + lr;
        #pragma unroll
        for (int j = 0; j < 8; ++j) {
            int col0 = wcB + j*16 + lg*4;
            float4 b4 = *(const float4*)(b1 + col0);
            float v0 = fmaxf(acc1[j][0] + b4.x, 0.f), v1 = fmaxf(acc1[j][1] + b4.y, 0.f);
            float v2 = fmaxf(acc1[j][2] + b4.z, 0.f), v3 = fmaxf(acc1[j][3] + b4.w, 0.f);
            *(uint2*)(F1 + row*512 + (((col0 >> 3) ^ (row & 7)) << 4) + (col0 & 7)*2)
                = make_uint2(cvt_pk_bf16(v0, v1), cvt_pk_bf16(v2, v3));
        }
    }
    __syncthreads();

    f32x4 acc2[2][8] = {};
    #pragma unroll
    for (int nh = 0; nh < 2; ++nh) {
        for (int s4 = 0; s4 < 4; ++s4) {
            int k0 = s4*64;
            #pragma unroll
            for (int i = 0; i < 4; ++i) {
                int slot = i*512 + tid;
                int row = slot >> 3, ch = slot & 7;
                GLOAD16(W2T + (size_t)(nh*256 + row)*256 + k0 + ((ch ^ (row & 7)) << 3),
                        BST + i*8192 + wave*1024);
            }
            __syncthreads();
            #pragma unroll
            for (int kk = 0; kk < 2; ++kk) {
                v8s af = *(const v8s*)(F1 + (wr + lr)*512 + ((s4*8 + ((kk*4 + lg) ^ lr7)) << 4));
                v8s bf[8];
                #pragma unroll
                for (int j = 0; j < 8; ++j)
                    bf[j] = *(const v8s*)(BST + (wcB + j*16 + lr)*128 + ((((kk<<2)|lg) ^ lr7) << 4));
                #pragma unroll
                for (int j = 0; j < 8; ++j)
                    acc2[nh][j] = __builtin_amdgcn_mfma_f32_16x16x32_bf16(bf[j], af, acc2[nh][j], 0, 0, 0);
            }
            __syncthreads();
        }
    }

    const int row = wr + lr;
    float s = 0.f, q = 0.f;
    #pragma unroll
    for (int nh = 0; nh < 2; ++nh) {
        #pragma unroll
        for (int j = 0; j < 8; ++j) {
            int col0 = nh*256 + wcB + j*16 + lg*4;
            float4 b4 = *(const float4*)(b2 + col0);
            uint2 hh = *(const uint2*)(H + row*1024 + ((((col0 & 511) >> 3) ^ (row & 7)) << 4) + (col0 & 7)*2);
            f32x4 a = acc2[nh][j];
            a[0] += b4.x + bflo(hh.x); a[1] += b4.y + bfhi(hh.x);
            a[2] += b4.z + bflo(hh.y); a[3] += b4.w + bfhi(hh.y);
            acc2[nh][j] = a;
            s += (a[0]+a[1]) + (a[2]+a[3]);
            q += (a[0]*a[0]+a[1]*a[1]) + (a[2]*a[2]+a[3]*a[3]);
        }
    }
    s += __shfl_xor(s, 16); s += __shfl_xor(s, 32);
    q += __shfl_xor(q, 16); q += __shfl_xor(q, 32);
    if (lg == 0) { Ps[row*2 + (wave >> 2)] = s; Pq[row*2 + (wave >> 2)] = q; }
    __syncthreads();
    float st = Ps[row*2] + Ps[row*2 + 1];
    float qt = Pq[row*2] + Pq[row*2 + 1];
    float mu = st * (1.f/512.f);
    float rs = rsqrtf(qt * (1.f/512.f) - mu*mu + 1e-5f);

    #pragma unroll
    for (int nh = 0; nh < 2; ++nh) {
        #pragma unroll
        for (int j = 0; j < 8; ++j) {
            int col0 = nh*256 + wcB + j*16 + lg*4;
            float4 gg = *(const float4*)(g2 + col0);
            float4 ee = *(const float4*)(be2 + col0);
            f32x4 a = acc2[nh][j];
            float4 o;
            o.x = (a[0]-mu)*rs*gg.x + ee.x;
            o.y = (a[1]-mu)*rs*gg.y + ee.y;
            o.z = (a[2]-mu)*rs*gg.z + ee.z;
            o.w = (a[3]-mu)*rs*gg.w + ee.w;
            *(float4*)(out + (size_t)(r0 + row)*512 + col0) = o;
        }
    }
}

// ---------------- launcher ----------------

extern "C" void kernel_launch(void* const* d_in, const int* in_sizes, int n_in,
                              void* d_out, int out_size, void* d_ws, size_t ws_size,
                              hipStream_t stream)
{
    const float* x   = (const float*)d_in[0];
    const float* Wq  = (const float*)d_in[1];
    const float* bq  = (const float*)d_in[2];
    const float* Wk  = (const float*)d_in[3];
    const float* bk  = (const float*)d_in[4];
    const float* Wv  = (const float*)d_in[5];
    const float* bv  = (const float*)d_in[6];
    const float* W1  = (const float*)d_in[7];
    const float* bf1 = (const float*)d_in[8];
    const float* W2  = (const float*)d_in[9];
    const float* bf2 = (const float*)d_in[10];
    const float* g1  = (const float*)d_in[11];
    const float* be1 = (const float*)d_in[12];
    const float* g2  = (const float*)d_in[13];
    const float* be2 = (const float*)d_in[14];

    char* ws = (char*)d_ws;
    const size_t MB = 1ull << 20;
    const size_t KB = 1024;
    u16* xb    = (u16*)(ws + 0);          // x bf16 — stays live through ffln
    u16* qb    = (u16*)(ws + 16*MB);
    u16* kb    = (u16*)(ws + 32*MB);
    u16* vT    = (u16*)(ws + 48*MB);      // v transposed [b][h][d][ne]
    u16* attnb = (u16*)(ws + 64*MB);      // attention output (own region)
    u16* WqkvT = (u16*)(ws + 80*MB);                 // [1536][512]
    u16* W1T   = (u16*)(ws + 80*MB + 1536*KB);       // [256][512]
    u16* W2T   = (u16*)(ws + 80*MB + 1792*KB);       // [512][256]
    (void)ws_size; (void)in_sizes; (void)n_in; (void)out_size;

    cvt_all_kernel<<<12288, 256, 0, stream>>>(x, xb, Wq, Wk, Wv, W1, W2, WqkvT, W1T, W2T);

    qkv_kernel<<<768, 512, 147456, stream>>>(xb, WqkvT, bq, bk, bv, qb, kb, vT);

    attn_kernel<<<256, 512, 132096, stream>>>(qb, kb, vT, attnb);

    ffln_kernel<<<256, 512, 132096, stream>>>(attnb, xb, g1, be1, W1T, bf1, W2T, bf2,
                                              g2, be2, (float*)d_out);
}

// Round 16
// 114.397 us; speedup vs baseline: 1.0855x; 1.0855x over previous
//
#include <hip/hip_runtime.h>

#define BS 32
#define NE 512
#define DMODEL 512
#define HEADS 8
#define EMB 64
#define FFH 256
#define MTOK (BS*NE)   // 16384

typedef unsigned short u16;
typedef short v8s __attribute__((ext_vector_type(8)));
typedef float f32x4 __attribute__((ext_vector_type(4)));
typedef u16 u16x4 __attribute__((ext_vector_type(4)));

#define GLOAD16(G, L) \
  __builtin_amdgcn_global_load_lds((const __attribute__((address_space(1))) unsigned int*)(G), \
      (__attribute__((address_space(3))) unsigned int*)(L), 16, 0, 0)

static __device__ __forceinline__ unsigned cvt_pk_bf16(float lo, float hi) {
    unsigned r;
    asm("v_cvt_pk_bf16_f32 %0, %1, %2" : "=v"(r) : "v"(lo), "v"(hi));
    return r;
}

static __device__ __forceinline__ u16 f2bf_bits(float f) {
    unsigned u = __float_as_uint(f);
    u += 0x7fffu + ((u >> 16) & 1u);   // round-to-nearest-even
    return (u16)(u >> 16);
}
static __device__ __forceinline__ float bflo(unsigned w) { return __uint_as_float(w << 16); }
static __device__ __forceinline__ float bfhi(unsigned w) { return __uint_as_float(w & 0xffff0000u); }

// ---------------- fused conversion: x linear + weight transpose via LDS tiles ----------------
// id < 8192: x f32 -> bf16 linear (float4 granules).
// id >= 8192: one 32x32 weight tile — coalesced f32 loads -> LDS -> coalesced bf16 row writes.
__global__ __launch_bounds__(256) void cvt_all_kernel(
    const float* __restrict__ x, u16* __restrict__ xb,
    const float* __restrict__ Wq, const float* __restrict__ Wk, const float* __restrict__ Wv,
    const float* __restrict__ W1, const float* __restrict__ W2,
    u16* __restrict__ WqkvT, u16* __restrict__ W1T, u16* __restrict__ W2T)
{
    const int id = blockIdx.x;
    const int tt = threadIdx.x;
    if (id < 8192) {
        int i = id*256 + tt;
        float4 v = ((const float4*)x)[i];
        u16x4 o = { f2bf_bits(v.x), f2bf_bits(v.y), f2bf_bits(v.z), f2bf_bits(v.w) };
        ((u16x4*)xb)[i] = o;
        return;
    }
    __shared__ float T[32][33];
    const int tid2 = id - 8192;        // 0..1023
    const float* src; u16* dst; int ldsrc, lddst, sr, sc;
    if (tid2 < 768) {                  // Wq/Wk/Wv: 512x512, 16x16 tiles each
        int w = tid2 >> 8, t = tid2 & 255;
        int tr = t >> 4, tc = t & 15;
        src = (w == 0) ? Wq : (w == 1) ? Wk : Wv;
        ldsrc = 512; sr = tr*32; sc = tc*32;
        dst = WqkvT + (size_t)(w*512 + sc)*512 + sr; lddst = 512;
    } else if (tid2 < 896) {           // W1: 512x256, 16x8 tiles
        int t = tid2 - 768;
        int tr = t >> 3, tc = t & 7;
        src = W1; ldsrc = 256; sr = tr*32; sc = tc*32;
        dst = W1T + (size_t)sc*512 + sr; lddst = 512;
    } else {                           // W2: 256x512, 8x16 tiles
        int t = tid2 - 896;
        int tr = t >> 4, tc = t & 15;
        src = W2; ldsrc = 512; sr = tr*32; sc = tc*32;
        dst = W2T + (size_t)sc*256 + sr; lddst = 256;
    }
    {
        int r = tt >> 3, c4 = (tt & 7) << 2;
        float4 v = *(const float4*)(src + (size_t)(sr + r)*ldsrc + sc + c4);
        T[r][c4] = v.x; T[r][c4+1] = v.y; T[r][c4+2] = v.z; T[r][c4+3] = v.w;
    }
    __syncthreads();
    {
        int n = tt >> 3, k4 = (tt & 7) << 2;
        u16x4 o = { f2bf_bits(T[k4][n]), f2bf_bits(T[k4+1][n]),
                    f2bf_bits(T[k4+2][n]), f2bf_bits(T[k4+3][n]) };
        *(u16x4*)(dst + (size_t)n*lddst + k4) = o;
    }
}

// ---------------- fused QKV GEMM (r14 dbuf structure — best measured: 44us) ----------------
__global__ __launch_bounds__(256, 2) void qkv_kernel(
    const u16* __restrict__ A, const u16* __restrict__ BT,
    const float* __restrict__ bsQ, const float* __restrict__ bsK, const float* __restrict__ bsV,
    u16* __restrict__ oQ, u16* __restrict__ oK, u16* __restrict__ oVT)
{
    __shared__ u16 Ab[2][128*64];
    __shared__ u16 Bb[2][128*64];
    const int tid = threadIdx.x;
    const int wave = tid >> 6, lane = tid & 63;
    const int lr = lane & 15, lg = lane >> 4, lr7 = lr & 7;
    const int id = blockIdx.x;
    const int rr = id & 7, qq = id >> 3;
    const int gk = qq / 12, colBlk = qq - gk*12;
    const int rowBlk = gk*8 + rr;
    const int aRow0 = rowBlk*128, bRow0 = colBlk*128;
    const int wlo = (wave >> 1)*64, wco = (wave & 1)*64;
    const int srow = tid >> 3, schunk = tid & 7;
    const int soff = ((schunk ^ (srow & 7)) << 3);
    const bool isV = (bRow0 >= 1024);

    auto stage = [&](int bsel, int k0) {
        #pragma unroll
        for (int i = 0; i < 4; ++i) {
            int row = i*32 + srow;
            GLOAD16(A  + (size_t)(aRow0 + row)*512 + k0 + soff, (char*)&Ab[bsel][0] + i*4096 + wave*1024);
            GLOAD16(BT + (size_t)(bRow0 + row)*512 + k0 + soff, (char*)&Bb[bsel][0] + i*4096 + wave*1024);
        }
    };

    stage(0, 0);

    f32x4 acc[4][4] = {};
    #pragma unroll
    for (int t = 0; t < 8; ++t) {
        const int cur = t & 1;
        asm volatile("s_waitcnt vmcnt(0)" ::: "memory");
        __builtin_amdgcn_s_barrier();
        if (t + 1 < 8) stage(cur ^ 1, (t + 1) * 64);
        #pragma unroll
        for (int kk = 0; kk < 2; ++kk) {
            v8s af[4], bf[4];
            #pragma unroll
            for (int i = 0; i < 4; ++i) {
                af[i] = *(const v8s*)((const char*)&Ab[cur][0] + (wlo + i*16 + lr)*128 + ((((kk<<2)|lg) ^ lr7) << 4));
                bf[i] = *(const v8s*)((const char*)&Bb[cur][0] + (wco + i*16 + lr)*128 + ((((kk<<2)|lg) ^ lr7) << 4));
            }
            if (isV) {
                #pragma unroll
                for (int i = 0; i < 4; ++i)
                    #pragma unroll
                    for (int j = 0; j < 4; ++j)
                        acc[i][j] = __builtin_amdgcn_mfma_f32_16x16x32_bf16(af[i], bf[j], acc[i][j], 0, 0, 0);
            } else {
                #pragma unroll
                for (int i = 0; i < 4; ++i)
                    #pragma unroll
                    for (int j = 0; j < 4; ++j)
                        acc[i][j] = __builtin_amdgcn_mfma_f32_16x16x32_bf16(bf[j], af[i], acc[i][j], 0, 0, 0);
            }
        }
    }

    if (isV) {
        #pragma unroll
        for (int j = 0; j < 4; ++j) {
            int col = (bRow0 & 511) + wco + j*16 + lr;
            float bv = bsV[col];
            int hh = col >> 6, d = col & 63;
            #pragma unroll
            for (int i = 0; i < 4; ++i) {
                int t0 = aRow0 + wlo + i*16 + lg*4;
                int bb = t0 >> 9, tr = t0 & 511;
                unsigned lo = cvt_pk_bf16(acc[i][j][0] + bv, acc[i][j][1] + bv);
                unsigned hi = cvt_pk_bf16(acc[i][j][2] + bv, acc[i][j][3] + bv);
                *(uint2*)(oVT + ((size_t)((bb*HEADS + hh)*EMB + d))*NE + tr) = make_uint2(lo, hi);
            }
        }
    } else {
        const int sel = (bRow0 >> 9) & 1;          // 0 = Q, 1 = K
        u16* dst = sel ? oK : oQ;
        const float* bias = sel ? bsK : bsQ;
        const int cb = bRow0 & 511;
        #pragma unroll
        for (int j = 0; j < 4; ++j) {
            int col0 = cb + wco + j*16 + lg*4;
            float4 b4 = *(const float4*)&bias[col0];
            #pragma unroll
            for (int i = 0; i < 4; ++i) {
                int row = aRow0 + wlo + i*16 + lr;
                float v0 = acc[i][j][0] + b4.x, v1 = acc[i][j][1] + b4.y;
                float v2 = acc[i][j][2] + b4.z, v3 = acc[i][j][3] + b4.w;
                if (sel == 0) {
                    const float SCL = 0.18033688011112042f;   // 0.125*log2(e)
                    v0 *= SCL; v1 *= SCL; v2 *= SCL; v3 *= SCL;
                }
                *(uint2*)(dst + (size_t)row*DMODEL + col0)
                    = make_uint2(cvt_pk_bf16(v0, v1), cvt_pk_bf16(v2, v3));
            }
        }
    }
}

// ---------------- attention (r14, unchanged) ----------------
__global__ __launch_bounds__(512, 2) void attn_kernel(
    const u16* __restrict__ Q, const u16* __restrict__ Kb,
    const u16* __restrict__ VT, u16* __restrict__ O)
{
    extern __shared__ char smem[];
    const int b = blockIdx.x >> 3, h = blockIdx.x & 7;
    const int tid = threadIdx.x, wave = tid >> 6, lane = tid & 63;
    const int lr = lane & 15, lg = lane >> 4, lr7 = lr & 7;

    const int srow = tid >> 3, schunk = tid & 7;
    const int soff = ((schunk ^ (srow & 7)) << 3);
    #pragma unroll
    for (int i = 0; i < 8; ++i)
        GLOAD16(Kb + (size_t)(b*NE + i*64 + srow)*DMODEL + h*EMB + soff,
                (char*)smem + i*8192 + wave*1024);
    #pragma unroll
    for (int i = 0; i < 8; ++i) {
        int row = i*8 + wave;
        GLOAD16(VT + (size_t)((b*HEADS + h)*EMB + row)*NE + lane*8,
                (char*)smem + 65536 + row*1040);
    }

    const int q0 = wave*64;
    v8s qa[4][2];
    #pragma unroll
    for (int ti = 0; ti < 4; ++ti) {
        const u16* qr = Q + (size_t)(b*NE + q0 + ti*16 + lr)*DMODEL + h*EMB;
        qa[ti][0] = *(const v8s*)(qr + lg*8);
        qa[ti][1] = *(const v8s*)(qr + 32 + lg*8);
    }
    __syncthreads();

    f32x4 o[4][4] = {};
    float ssum[4] = {0.f, 0.f, 0.f, 0.f};

    #pragma unroll 1
    for (int c = 0; c < 16; ++c) {
        const char* kr0 = (const char*)smem + ((2*c  )*16 + lr)*128;
        const char* kr1 = (const char*)smem + ((2*c+1)*16 + lr)*128;
        v8s kA0 = *(const v8s*)(kr0 + ((lg ^ lr7) << 4));
        v8s kA1 = *(const v8s*)(kr0 + (((4|lg) ^ lr7) << 4));
        v8s kB0 = *(const v8s*)(kr1 + ((lg ^ lr7) << 4));
        v8s kB1 = *(const v8s*)(kr1 + (((4|lg) ^ lr7) << 4));
        v8s vf[4];
        #pragma unroll
        for (int dt = 0; dt < 4; ++dt) {
            const char* vr = (const char*)smem + 65536 + (dt*16 + lr)*1040 + c*64 + lg*8;
            uint2 lo = *(const uint2*)(vr);
            uint2 hi = *(const uint2*)(vr + 32);
            uint4 u = make_uint4(lo.x, lo.y, hi.x, hi.y);
            vf[dt] = *(v8s*)&u;
        }
        #pragma unroll
        for (int ti = 0; ti < 4; ++ti) {
            __builtin_amdgcn_s_setprio(1);
            f32x4 s0 = {0.f,0.f,0.f,0.f}, s1 = {0.f,0.f,0.f,0.f};
            s0 = __builtin_amdgcn_mfma_f32_16x16x32_bf16(kA0, qa[ti][0], s0, 0, 0, 0);
            s0 = __builtin_amdgcn_mfma_f32_16x16x32_bf16(kA1, qa[ti][1], s0, 0, 0, 0);
            s1 = __builtin_amdgcn_mfma_f32_16x16x32_bf16(kB0, qa[ti][0], s1, 0, 0, 0);
            s1 = __builtin_amdgcn_mfma_f32_16x16x32_bf16(kB1, qa[ti][1], s1, 0, 0, 0);
            __builtin_amdgcn_s_setprio(0);
            float p0 = exp2f(s0[0]), p1 = exp2f(s0[1]), p2 = exp2f(s0[2]), p3 = exp2f(s0[3]);
            float r0 = exp2f(s1[0]), r1 = exp2f(s1[1]), r2 = exp2f(s1[2]), r3 = exp2f(s1[3]);
            ssum[ti] += ((p0 + p1) + (p2 + p3)) + ((r0 + r1) + (r2 + r3));
            unsigned a0 = cvt_pk_bf16(p0, p1), a1 = cvt_pk_bf16(p2, p3);
            unsigned b0 = cvt_pk_bf16(r0, r1), b1 = cvt_pk_bf16(r2, r3);
            uint4 pu = make_uint4(a0, a1, b0, b1);
            v8s pb = *(v8s*)&pu;
            __builtin_amdgcn_s_setprio(1);
            #pragma unroll
            for (int dt = 0; dt < 4; ++dt)
                o[ti][dt] = __builtin_amdgcn_mfma_f32_16x16x32_bf16(vf[dt], pb, o[ti][dt], 0, 0, 0);
            __builtin_amdgcn_s_setprio(0);
        }
    }

    __syncthreads();

    float rinv[4];
    #pragma unroll
    for (int ti = 0; ti < 4; ++ti) {
        float v = ssum[ti];
        v += __shfl_xor(v, 16);
        v += __shfl_xor(v, 32);
        rinv[ti] = 1.f / v;
    }

    char* ow = (char*)smem + wave*10240;
    #pragma unroll
    for (int ti = 0; ti < 4; ++ti) {
        #pragma unroll
        for (int dt = 0; dt < 4; ++dt) {
            unsigned d0 = cvt_pk_bf16(o[ti][dt][0]*rinv[ti], o[ti][dt][1]*rinv[ti]);
            unsigned d1 = cvt_pk_bf16(o[ti][dt][2]*rinv[ti], o[ti][dt][3]*rinv[ti]);
            *(uint2*)(ow + (ti*16 + lr)*160 + dt*32 + lg*8) = make_uint2(d0, d1);
        }
    }
    __asm__ volatile("s_waitcnt lgkmcnt(0)" ::: "memory");
    #pragma unroll
    for (int it = 0; it < 8; ++it) {
        int rr2 = it*8 + (lane >> 3);
        uint4 v = *(const uint4*)(ow + rr2*160 + (lane & 7)*16);
        *(uint4*)(O + (size_t)(b*NE + q0 + rr2)*DMODEL + h*EMB + (lane & 7)*8) = v;
    }
}

// ---------------- grand fused LN1 + FF1 + relu + FF2 + residual + LN2 (full dbuf) ----------------
// LDS: H [0,64K) | F1/BSTb [64K,96K) | BSTa [96K,128K) | partials @128K.
// FF1 dbufs W1 stages between BSTa and the F1 region (free until FF1 done).
// FF2 preloads LN2 residual to regs, freeing H (=2x32KB) to dbuf W2 stages.
__global__ __launch_bounds__(512) void ffln_kernel(
    const u16* __restrict__ At, const u16* __restrict__ xb,
    const float* __restrict__ g1, const float* __restrict__ be1,
    const u16* __restrict__ W1T, const float* __restrict__ b1,
    const u16* __restrict__ W2T, const float* __restrict__ b2,
    const float* __restrict__ g2, const float* __restrict__ be2,
    float* __restrict__ out)
{
    extern __shared__ char smem[];
    char* H    = smem;              // [64 rows][1024B], chunk16 ^ (row&7)
    char* F1   = smem + 65536;      // [64 rows][512B] (after FF1; FF1 bufB before that)
    char* BSTa = smem + 98304;      // 32KB weight staging buf A
    float* Ps = (float*)(smem + 131072);   // [64][2] sum partials
    float* Pq = Ps + 128;                  // [64][2] sq partials

    const int tid = threadIdx.x, wave = tid >> 6, lane = tid & 63;
    const int lr = lane & 15, lg = lane >> 4, lr7 = lr & 7;
    const int r0 = blockIdx.x * 64;

    // ---- LN1: wave handles 8 rows; lane covers cols lane*8..+7 ----
    #pragma unroll
    for (int it = 0; it < 8; ++it) {
        int r = wave*8 + it;
        uint4 av = *(const uint4*)(At + (size_t)(r0 + r)*512 + lane*8);
        uint4 xv = *(const uint4*)(xb + (size_t)(r0 + r)*512 + lane*8);
        float v0 = bflo(av.x) + bflo(xv.x), v1 = bfhi(av.x) + bfhi(xv.x);
        float v2 = bflo(av.y) + bflo(xv.y), v3 = bfhi(av.y) + bfhi(xv.y);
        float v4 = bflo(av.z) + bflo(xv.z), v5 = bfhi(av.z) + bfhi(xv.z);
        float v6 = bflo(av.w) + bflo(xv.w), v7 = bfhi(av.w) + bfhi(xv.w);
        float s = ((v0+v1)+(v2+v3)) + ((v4+v5)+(v6+v7));
        float q = ((v0*v0+v1*v1)+(v2*v2+v3*v3)) + ((v4*v4+v5*v5)+(v6*v6+v7*v7));
        #pragma unroll
        for (int d = 1; d < 64; d <<= 1) { s += __shfl_xor(s, d); q += __shfl_xor(q, d); }
        float mu = s * (1.f/512.f);
        float rs = rsqrtf(q * (1.f/512.f) - mu*mu + 1e-5f);
        float4 gA = *(const float4*)(g1 + lane*8), gB = *(const float4*)(g1 + lane*8 + 4);
        float4 eA = *(const float4*)(be1 + lane*8), eB = *(const float4*)(be1 + lane*8 + 4);
        float h0 = (v0-mu)*rs*gA.x + eA.x, h1 = (v1-mu)*rs*gA.y + eA.y;
        float h2 = (v2-mu)*rs*gA.z + eA.z, h3 = (v3-mu)*rs*gA.w + eA.w;
        float h4 = (v4-mu)*rs*gB.x + eB.x, h5 = (v5-mu)*rs*gB.y + eB.y;
        float h6 = (v6-mu)*rs*gB.z + eB.z, h7 = (v7-mu)*rs*gB.w + eB.w;
        uint4 hw = make_uint4(cvt_pk_bf16(h0,h1), cvt_pk_bf16(h2,h3),
                              cvt_pk_bf16(h4,h5), cvt_pk_bf16(h6,h7));
        *(uint4*)(H + r*1024 + ((lane ^ (r & 7)) << 4)) = hw;
    }
    __syncthreads();

    const int wr = (wave & 3)*16, wcB = (wave >> 2)*128;

    // ---- FF1: 64x256 = h @ W1; dbuf stages between BSTa and F1-region ----
    auto stageW1 = [&](char* buf, int s8) {
        int k0 = s8*64;
        #pragma unroll
        for (int i = 0; i < 4; ++i) {
            int slot = i*512 + tid;
            int row = slot >> 3, ch = slot & 7;
            GLOAD16(W1T + (size_t)row*512 + k0 + ((ch ^ (row & 7)) << 3),
                    buf + i*8192 + wave*1024);
        }
    };
    stageW1(BSTa, 0);
    f32x4 acc1[8] = {};
    #pragma unroll
    for (int s8 = 0; s8 < 8; ++s8) {
        char* cur = (s8 & 1) ? F1 : BSTa;
        asm volatile("s_waitcnt vmcnt(0)" ::: "memory");
        __builtin_amdgcn_s_barrier();
        if (s8 + 1 < 8) stageW1((s8 & 1) ? BSTa : F1, s8 + 1);
        #pragma unroll
        for (int kk = 0; kk < 2; ++kk) {
            v8s af = *(const v8s*)(H + (wr + lr)*1024 + (((s8*8 + kk*4 + lg) ^ lr7) << 4));
            v8s bf[8];
            #pragma unroll
            for (int j = 0; j < 8; ++j)
                bf[j] = *(const v8s*)(cur + (wcB + j*16 + lr)*128 + ((((kk<<2)|lg) ^ lr7) << 4));
            #pragma unroll
            for (int j = 0; j < 8; ++j)
                acc1[j] = __builtin_amdgcn_mfma_f32_16x16x32_bf16(bf[j], af, acc1[j], 0, 0, 0);
        }
    }
    __syncthreads();   // all waves past final FF1 compute; F1 region free for real F1

    // relu + bias -> F1 (swizzled)
    {
        int row = wr + lr;
        #pragma unroll
        for (int j = 0; j < 8; ++j) {
            int col0 = wcB + j*16 + lg*4;
            float4 b4 = *(const float4*)(b1 + col0);
            float v0 = fmaxf(acc1[j][0] + b4.x, 0.f), v1 = fmaxf(acc1[j][1] + b4.y, 0.f);
            float v2 = fmaxf(acc1[j][2] + b4.z, 0.f), v3 = fmaxf(acc1[j][3] + b4.w, 0.f);
            *(uint2*)(F1 + row*512 + (((col0 >> 3) ^ (row & 7)) << 4) + (col0 & 7)*2)
                = make_uint2(cvt_pk_bf16(v0, v1), cvt_pk_bf16(v2, v3));
        }
    }

    // preload LN2 residual (h) into registers, freeing H for FF2 staging
    const int row = wr + lr;
    uint2 hres[2][8];
    #pragma unroll
    for (int nh = 0; nh < 2; ++nh)
        #pragma unroll
        for (int j = 0; j < 8; ++j) {
            int col0 = nh*256 + wcB + j*16 + lg*4;
            hres[nh][j] = *(const uint2*)(H + row*1024 +
                            ((((col0 & 511) >> 3) ^ (row & 7)) << 4) + (col0 & 7)*2);
        }
    __syncthreads();   // F1 writes + residual reads done before FF2 stages into H

    // ---- FF2: 64x512 = f1 @ W2; dbuf stages between H[0:32K) and H[32K:64K) ----
    auto stageW2 = [&](char* buf, int g) {    // g = nh*4 + s4
        int nh = g >> 2, k0 = (g & 3)*64;
        #pragma unroll
        for (int i = 0; i < 4; ++i) {
            int slot = i*512 + tid;
            int rw = slot >> 3, ch = slot & 7;
            GLOAD16(W2T + (size_t)(nh*256 + rw)*256 + k0 + ((ch ^ (rw & 7)) << 3),
                    buf + i*8192 + wave*1024);
        }
    };
    stageW2(H, 0);
    f32x4 acc2[2][8] = {};
    #pragma unroll
    for (int g = 0; g < 8; ++g) {
        char* cur = (g & 1) ? (H + 32768) : H;
        asm volatile("s_waitcnt vmcnt(0)" ::: "memory");
        __builtin_amdgcn_s_barrier();
        if (g + 1 < 8) stageW2((g & 1) ? H : (H + 32768), g + 1);
        const int nh = g >> 2, s4 = g & 3;
        #pragma unroll
        for (int kk = 0; kk < 2; ++kk) {
            v8s af = *(const v8s*)(F1 + (wr + lr)*512 + (((s4*8 + kk*4 + lg) ^ lr7) << 4));
            v8s bf[8];
            #pragma unroll
            for (int j = 0; j < 8; ++j)
                bf[j] = *(const v8s*)(cur + (wcB + j*16 + lr)*128 + ((((kk<<2)|lg) ^ lr7) << 4));
            #pragma unroll
            for (int j = 0; j < 8; ++j)
                acc2[nh][j] = __builtin_amdgcn_mfma_f32_16x16x32_bf16(bf[j], af, acc2[nh][j], 0, 0, 0);
        }
    }

    // ---- bias + residual(regs) + LN2 stats (each lane owns ONE token row) ----
    float s = 0.f, q = 0.f;
    #pragma unroll
    for (int nh = 0; nh < 2; ++nh) {
        #pragma unroll
        for (int j = 0; j < 8; ++j) {
            int col0 = nh*256 + wcB + j*16 + lg*4;
            float4 b4 = *(const float4*)(b2 + col0);
            uint2 hh = hres[nh][j];
            f32x4 a = acc2[nh][j];
            a[0] += b4.x + bflo(hh.x); a[1] += b4.y + bfhi(hh.x);
            a[2] += b4.z + bflo(hh.y); a[3] += b4.w + bfhi(hh.y);
            acc2[nh][j] = a;
            s += (a[0]+a[1]) + (a[2]+a[3]);
            q += (a[0]*a[0]+a[1]*a[1]) + (a[2]*a[2]+a[3]*a[3]);
        }
    }
    s += __shfl_xor(s, 16); s += __shfl_xor(s, 32);
    q += __shfl_xor(q, 16); q += __shfl_xor(q, 32);
    __syncthreads();   // FF2 reads done (also orders partial writes below)
    if (lg == 0) { Ps[row*2 + (wave >> 2)] = s; Pq[row*2 + (wave >> 2)] = q; }
    __syncthreads();
    float st = Ps[row*2] + Ps[row*2 + 1];
    float qt = Pq[row*2] + Pq[row*2 + 1];
    float mu = st * (1.f/512.f);
    float rs = rsqrtf(qt * (1.f/512.f) - mu*mu + 1e-5f);

    #pragma unroll
    for (int nh = 0; nh < 2; ++nh) {
        #pragma unroll
        for (int j = 0; j < 8; ++j) {
            int col0 = nh*256 + wcB + j*16 + lg*4;
            float4 gg = *(const float4*)(g2 + col0);
            float4 ee = *(const float4*)(be2 + col0);
            f32x4 a = acc2[nh][j];
            float4 o;
            o.x = (a[0]-mu)*rs*gg.x + ee.x;
            o.y = (a[1]-mu)*rs*gg.y + ee.y;
            o.z = (a[2]-mu)*rs*gg.z + ee.z;
            o.w = (a[3]-mu)*rs*gg.w + ee.w;
            *(float4*)(out + (size_t)(r0 + row)*512 + col0) = o;
        }
    }
}

// ---------------- launcher ----------------

extern "C" void kernel_launch(void* const* d_in, const int* in_sizes, int n_in,
                              void* d_out, int out_size, void* d_ws, size_t ws_size,
                              hipStream_t stream)
{
    const float* x   = (const float*)d_in[0];
    const float* Wq  = (const float*)d_in[1];
    const float* bq  = (const float*)d_in[2];
    const float* Wk  = (const float*)d_in[3];
    const float* bk  = (const float*)d_in[4];
    const float* Wv  = (const float*)d_in[5];
    const float* bv  = (const float*)d_in[6];
    const float* W1  = (const float*)d_in[7];
    const float* bf1 = (const float*)d_in[8];
    const float* W2  = (const float*)d_in[9];
    const float* bf2 = (const float*)d_in[10];
    const float* g1  = (const float*)d_in[11];
    const float* be1 = (const float*)d_in[12];
    const float* g2  = (const float*)d_in[13];
    const float* be2 = (const float*)d_in[14];

    char* ws = (char*)d_ws;
    const size_t MB = 1ull << 20;
    const size_t KB = 1024;
    u16* xb    = (u16*)(ws + 0);          // x bf16 — stays live through ffln
    u16* qb    = (u16*)(ws + 16*MB);
    u16* kb    = (u16*)(ws + 32*MB);
    u16* vT    = (u16*)(ws + 48*MB);      // v transposed [b][h][d][ne]
    u16* attnb = (u16*)(ws + 64*MB);      // attention output (own region)
    u16* WqkvT = (u16*)(ws + 80*MB);                 // [1536][512]
    u16* W1T   = (u16*)(ws + 80*MB + 1536*KB);       // [256][512]
    u16* W2T   = (u16*)(ws + 80*MB + 1792*KB);       // [512][256]
    (void)ws_size; (void)in_sizes; (void)n_in; (void)out_size;

    cvt_all_kernel<<<9216, 256, 0, stream>>>(x, xb, Wq, Wk, Wv, W1, W2, WqkvT, W1T, W2T);

    qkv_kernel<<<1536, 256, 0, stream>>>(xb, WqkvT, bq, bk, bv, qb, kb, vT);

    attn_kernel<<<256, 512, 132096, stream>>>(qb, kb, vT, attnb);

    ffln_kernel<<<256, 512, 132096, stream>>>(attnb, xb, g1, be1, W1T, bf1, W2T, bf2,
                                              g2, be2, (float*)d_out);
}